// Round 2
// baseline (209.253 us; speedup 1.0000x reference)
//
#include <hip/hip_runtime.h>
#include <math.h>

#define LDP 68   // padded row stride for LDS tiles (float4-aligned, low-conflict)

// ---------------------------------------------------------------------------
// Quantum constants: psi0 (256 amplitudes) from params, then
// A_q = <Z_q>_psi0, B_q = <X_q>_psi0. ab[0..7]=A, ab[8..15]=B.
// Bit convention: qubit q <-> bit (7-q) of flat index (C-order flatten).
// ---------------------------------------------------------------------------
__global__ __launch_bounds__(256) void qconsts_kernel(const float* __restrict__ params,
                                                      float* __restrict__ ab) {
    __shared__ float st[256];
    __shared__ float red[256];
    const int tid = threadIdx.x;
    st[tid] = (tid == 0) ? 1.0f : 0.0f;
    __syncthreads();
    for (int l = 0; l < 2; ++l) {
        for (int q = 0; q < 8; ++q) {
            float h = 0.5f * params[l * 8 + q];
            float c = cosf(h), s = sinf(h);
            int str = 1 << (7 - q);
            if ((tid & str) == 0) {
                float s0 = st[tid], s1 = st[tid + str];
                st[tid]       = c * s0 - s * s1;
                st[tid + str] = s * s0 + c * s1;
            }
            __syncthreads();
        }
        for (int q = 0; q < 8; ++q) {
            int cw = q, tw = (q + 1) & 7;          // ring: (0,1)...(6,7),(7,0)
            int cs = 1 << (7 - cw), ts = 1 << (7 - tw);
            if ((tid & cs) && !(tid & ts)) {       // control=1, target=0: swap pair
                float a = st[tid], b = st[tid ^ ts];
                st[tid] = b;
                st[tid ^ ts] = a;
            }
            __syncthreads();
        }
    }
    float amp = st[tid];
    for (int q = 0; q < 8; ++q) {
        int str = 1 << (7 - q);
        float za = amp * amp * ((tid & str) ? -1.0f : 1.0f);
        float xb = ((tid & str) == 0) ? 2.0f * amp * st[tid ^ str] : 0.0f;
        red[tid] = za; __syncthreads();
        for (int off = 128; off; off >>= 1) { if (tid < off) red[tid] += red[tid + off]; __syncthreads(); }
        if (tid == 0) ab[q] = red[0];
        __syncthreads();
        red[tid] = xb; __syncthreads();
        for (int off = 128; off; off >>= 1) { if (tid < off) red[tid] += red[tid + off]; __syncthreads(); }
        if (tid == 0) ab[8 + q] = red[0];
        __syncthreads();
    }
}

// ---------------------------------------------------------------------------
// Shared GEMM helpers: 64x64 tile, BK=32, 256 threads, 4x4 per thread.
// LDS layout transposed to [kk][row] so fragments are ds_read_b128.
// ---------------------------------------------------------------------------
__device__ __forceinline__ void stage_nt(const float* __restrict__ A, const float* __restrict__ B,
                                         int lda, int ldb, int k0,
                                         float (*As)[LDP], float (*Bs)[LDP], int tid) {
#pragma unroll
    for (int it = 0; it < 2; ++it) {
        int fi = tid + it * 256;           // 512 float4s = 64 rows x 32 cols
        int row = fi >> 3;
        int col = (fi & 7) << 2;
        float4 va = *(const float4*)(A + (size_t)row * lda + k0 + col);
        As[col + 0][row] = va.x; As[col + 1][row] = va.y;
        As[col + 2][row] = va.z; As[col + 3][row] = va.w;
        float4 vb = *(const float4*)(B + (size_t)row * ldb + k0 + col);
        Bs[col + 0][row] = vb.x; Bs[col + 1][row] = vb.y;
        Bs[col + 2][row] = vb.z; Bs[col + 3][row] = vb.w;
    }
}

__device__ __forceinline__ void tile_fma(const float (*As)[LDP], const float (*Bs)[LDP],
                                         float acc[4][4], int tx, int ty) {
#pragma unroll
    for (int kk = 0; kk < 32; ++kk) {
        float4 av = *(const float4*)&As[kk][ty << 2];
        float4 bv = *(const float4*)&Bs[kk][tx << 2];
        float a[4] = {av.x, av.y, av.z, av.w};
        float b[4] = {bv.x, bv.y, bv.z, bv.w};
#pragma unroll
        for (int i = 0; i < 4; ++i)
#pragma unroll
            for (int j = 0; j < 4; ++j)
                acc[i][j] = fmaf(a[i], b[j], acc[i][j]);
    }
}

// ---------------------------------------------------------------------------
// QKV: C[m,n] = sum_k x[m,k] * W[n,k]   (NT), z selects Wq/Wk/Wv.
// ---------------------------------------------------------------------------
__global__ __launch_bounds__(256) void qkv_kernel(const float* __restrict__ x,
                                                  const float* __restrict__ Wq,
                                                  const float* __restrict__ Wk,
                                                  const float* __restrict__ Wv,
                                                  float* __restrict__ qb,
                                                  float* __restrict__ kb,
                                                  float* __restrict__ vb) {
    __shared__ float As[32][LDP];
    __shared__ float Bs[32][LDP];
    const int tid = threadIdx.x;
    const int tx = tid & 15, ty = tid >> 4;
    const int m0 = blockIdx.y << 6, n0 = blockIdx.x << 6;
    const int z = blockIdx.z;
    const float* W = (z == 0) ? Wq : ((z == 1) ? Wk : Wv);
    float* C = (z == 0) ? qb : ((z == 1) ? kb : vb);
    const float* A = x + (size_t)m0 * 512;
    const float* B = W + (size_t)n0 * 512;
    float acc[4][4] = {};
    for (int k0 = 0; k0 < 512; k0 += 32) {
        stage_nt(A, B, 512, 512, k0, As, Bs, tid);
        __syncthreads();
        tile_fma(As, Bs, acc, tx, ty);
        __syncthreads();
    }
#pragma unroll
    for (int i = 0; i < 4; ++i) {
        float4 o = {acc[i][0], acc[i][1], acc[i][2], acc[i][3]};
        *(float4*)(C + (size_t)(m0 + (ty << 2) + i) * 512 + (n0 + (tx << 2))) = o;
    }
}

// ---------------------------------------------------------------------------
// Scores: S[b,t,s] = (q[b,t,:] . k[b,s,:]) * scale   (batched NT)
// ---------------------------------------------------------------------------
__global__ __launch_bounds__(256) void scores_kernel(const float* __restrict__ qb,
                                                     const float* __restrict__ kb,
                                                     float* __restrict__ sb) {
    __shared__ float As[32][LDP];
    __shared__ float Bs[32][LDP];
    const int tid = threadIdx.x;
    const int tx = tid & 15, ty = tid >> 4;
    const int m0 = blockIdx.y << 6, n0 = blockIdx.x << 6;
    const int z = blockIdx.z;
    const float* A = qb + (size_t)z * 1024 * 512 + (size_t)m0 * 512;
    const float* B = kb + (size_t)z * 1024 * 512 + (size_t)n0 * 512;
    float* C = sb + (size_t)z * 1024 * 1024;
    const float scale = 0.044194173824159216f;   // 1/sqrt(512)
    float acc[4][4] = {};
    for (int k0 = 0; k0 < 512; k0 += 32) {
        stage_nt(A, B, 512, 512, k0, As, Bs, tid);
        __syncthreads();
        tile_fma(As, Bs, acc, tx, ty);
        __syncthreads();
    }
#pragma unroll
    for (int i = 0; i < 4; ++i) {
        float4 o = {acc[i][0] * scale, acc[i][1] * scale, acc[i][2] * scale, acc[i][3] * scale};
        *(float4*)(C + (size_t)(m0 + (ty << 2) + i) * 1024 + (n0 + (tx << 2))) = o;
    }
}

// ---------------------------------------------------------------------------
// Row softmax over 1024 entries; one block per row.
// ---------------------------------------------------------------------------
__global__ __launch_bounds__(256) void softmax_kernel(float* __restrict__ S) {
    const int row = blockIdx.x;
    float* p = S + (size_t)row * 1024;
    const int tid = threadIdx.x;
    float4 v = ((float4*)p)[tid];
    float m = fmaxf(fmaxf(v.x, v.y), fmaxf(v.z, v.w));
#pragma unroll
    for (int off = 32; off; off >>= 1) m = fmaxf(m, __shfl_xor(m, off));
    __shared__ float sm[4];
    __shared__ float ss[4];
    const int wid = tid >> 6, lane = tid & 63;
    if (lane == 0) sm[wid] = m;
    __syncthreads();
    m = fmaxf(fmaxf(sm[0], sm[1]), fmaxf(sm[2], sm[3]));
    float e0 = expf(v.x - m), e1 = expf(v.y - m), e2 = expf(v.z - m), e3 = expf(v.w - m);
    float s = e0 + e1 + e2 + e3;
#pragma unroll
    for (int off = 32; off; off >>= 1) s += __shfl_xor(s, off);
    if (lane == 0) ss[wid] = s;
    __syncthreads();
    s = ss[0] + ss[1] + ss[2] + ss[3];
    float r = 1.0f / s;
    float4 o = {e0 * r, e1 * r, e2 * r, e3 * r};
    ((float4*)p)[tid] = o;
}

// ---------------------------------------------------------------------------
// PV (NN): o[t,e] = sum_s w[t,s] * v[s,e], fused quantum epilogue:
//   out = cos(o)*A[e&7] - sin(o)*B[e&7]
// ---------------------------------------------------------------------------
__global__ __launch_bounds__(256) void pv_kernel(const float* __restrict__ Wt,
                                                 const float* __restrict__ V,
                                                 float* __restrict__ out,
                                                 const float* __restrict__ ab) {
    __shared__ float As[32][LDP];
    __shared__ float Bs[32][LDP];
    const int tid = threadIdx.x;
    const int tx = tid & 15, ty = tid >> 4;
    const int m0 = blockIdx.y << 6, n0 = blockIdx.x << 6;
    const int z = blockIdx.z;
    const float* A = Wt + (size_t)z * 1024 * 1024 + (size_t)m0 * 1024;
    const float* B = V + (size_t)z * 1024 * 512 + n0;
    float* C = out + (size_t)z * 1024 * 512;
    float acc[4][4] = {};
    for (int k0 = 0; k0 < 1024; k0 += 32) {
#pragma unroll
        for (int it = 0; it < 2; ++it) {
            int fi = tid + it * 256;
            int row = fi >> 3, col = (fi & 7) << 2;       // A: 64 rows x 32 k
            float4 va = *(const float4*)(A + (size_t)row * 1024 + k0 + col);
            As[col + 0][row] = va.x; As[col + 1][row] = va.y;
            As[col + 2][row] = va.z; As[col + 3][row] = va.w;
            int brow = fi >> 4, bcol = (fi & 15) << 2;    // B: 32 k x 64 cols (direct)
            float4 vb = *(const float4*)(B + (size_t)(k0 + brow) * 512 + bcol);
            *(float4*)&Bs[brow][bcol] = vb;
        }
        __syncthreads();
        tile_fma(As, Bs, acc, tx, ty);
        __syncthreads();
    }
    float cAl[4], cAh[4], cBl[4], cBh[4];
#pragma unroll
    for (int j = 0; j < 4; ++j) {
        cAl[j] = ab[j];     cAh[j] = ab[4 + j];
        cBl[j] = ab[8 + j]; cBh[j] = ab[12 + j];
    }
    const bool hi = (tx & 1);                 // (n0+tx*4+j)&7 = 4*(tx&1)+j
#pragma unroll
    for (int i = 0; i < 4; ++i) {
        float4 o;
        float* op = &o.x;
#pragma unroll
        for (int j = 0; j < 4; ++j) {
            float Aq = hi ? cAh[j] : cAl[j];
            float Bq = hi ? cBh[j] : cBl[j];
            float sn, cs;
            sincosf(acc[i][j], &sn, &cs);
            op[j] = cs * Aq - sn * Bq;
        }
        *(float4*)(C + (size_t)(m0 + (ty << 2) + i) * 512 + (n0 + (tx << 2))) = o;
    }
}

// ---------------------------------------------------------------------------
extern "C" void kernel_launch(void* const* d_in, const int* in_sizes, int n_in,
                              void* d_out, int out_size, void* d_ws, size_t ws_size,
                              hipStream_t stream) {
    const float* x      = (const float*)d_in[0];
    const float* Wq     = (const float*)d_in[1];
    const float* Wk     = (const float*)d_in[2];
    const float* Wv     = (const float*)d_in[3];
    const float* params = (const float*)d_in[4];
    float* out = (float*)d_out;
    float* ws  = (float*)d_ws;

    float* ab = ws;                         // 16 floats
    float* qb = ws + 64;                    // 2048*512
    float* kb = qb + 2048 * 512;            // 2048*512
    float* vb = kb + 2048 * 512;            // 2048*512
    float* sb = vb + 2048 * 512;            // 2*1024*1024

    hipLaunchKernelGGL(qconsts_kernel, dim3(1), dim3(256), 0, stream, params, ab);
    hipLaunchKernelGGL(qkv_kernel, dim3(8, 32, 3), dim3(256), 0, stream,
                       x, Wq, Wk, Wv, qb, kb, vb);
    hipLaunchKernelGGL(scores_kernel, dim3(16, 16, 2), dim3(256), 0, stream, qb, kb, sb);
    hipLaunchKernelGGL(softmax_kernel, dim3(2048), dim3(256), 0, stream, sb);
    hipLaunchKernelGGL(pv_kernel, dim3(8, 16, 2), dim3(256), 0, stream, sb, vb, out, ab);
}

// Round 3
// 126.273 us; speedup vs baseline: 1.6571x; 1.6571x over previous
//
#include <hip/hip_runtime.h>
#include <math.h>

typedef __attribute__((ext_vector_type(8))) short bf16x8;
typedef __attribute__((ext_vector_type(4))) float f32x4;

#define LDS_LD 40   // shorts per LDS tile row: 32 bf16 + 8 pad (80B, 16B-aligned)

__device__ __forceinline__ ushort f2b(float f) {   // fp32 -> bf16 RNE
    unsigned u = __float_as_uint(f);
    return (ushort)((u + 0x7FFFu + ((u >> 16) & 1u)) >> 16);
}

// ---------------------------------------------------------------------------
// Quantum constants: A_q = <Z_q>_psi0, B_q = <X_q>_psi0 (16 floats).
// z_q(theta) = cos(theta)*A_q - sin(theta)*B_q  collapses the whole circuit.
// ---------------------------------------------------------------------------
__global__ __launch_bounds__(256) void qconsts_kernel(const float* __restrict__ params,
                                                      float* __restrict__ ab) {
    __shared__ float st[256];
    __shared__ float red[256];
    const int tid = threadIdx.x;
    st[tid] = (tid == 0) ? 1.0f : 0.0f;
    __syncthreads();
    for (int l = 0; l < 2; ++l) {
        for (int q = 0; q < 8; ++q) {
            float h = 0.5f * params[l * 8 + q];
            float c = cosf(h), s = sinf(h);
            int str = 1 << (7 - q);
            if ((tid & str) == 0) {
                float s0 = st[tid], s1 = st[tid + str];
                st[tid]       = c * s0 - s * s1;
                st[tid + str] = s * s0 + c * s1;
            }
            __syncthreads();
        }
        for (int q = 0; q < 8; ++q) {
            int cw = q, tw = (q + 1) & 7;
            int cs = 1 << (7 - cw), ts = 1 << (7 - tw);
            if ((tid & cs) && !(tid & ts)) {
                float a = st[tid], b = st[tid ^ ts];
                st[tid] = b;
                st[tid ^ ts] = a;
            }
            __syncthreads();
        }
    }
    float amp = st[tid];
    for (int q = 0; q < 8; ++q) {
        int str = 1 << (7 - q);
        float za = amp * amp * ((tid & str) ? -1.0f : 1.0f);
        float xb = ((tid & str) == 0) ? 2.0f * amp * st[tid ^ str] : 0.0f;
        red[tid] = za; __syncthreads();
        for (int off = 128; off; off >>= 1) { if (tid < off) red[tid] += red[tid + off]; __syncthreads(); }
        if (tid == 0) ab[q] = red[0];
        __syncthreads();
        red[tid] = xb; __syncthreads();
        for (int off = 128; off; off >>= 1) { if (tid < off) red[tid] += red[tid + off]; __syncthreads(); }
        if (tid == 0) ab[8 + q] = red[0];
        __syncthreads();
    }
}

// ---------------------------------------------------------------------------
// Shared MFMA tile helpers: 64x64 tile, BK=32, 256 thr = 4 waves, each wave
// a 32x32 sub-tile (2x2 frags of 16x16x32 bf16). LDS [row][k] K-contiguous.
// ---------------------------------------------------------------------------
__device__ __forceinline__ void stage_f32(const float* __restrict__ A, const float* __restrict__ B,
                                          int lda, int ldb, int k0,
                                          short (*As)[LDS_LD], short (*Bs)[LDS_LD], int tid) {
    const int row = tid >> 2, quad = tid & 3;
    {
        const float* p = A + (size_t)row * lda + k0 + quad * 8;
        float4 v0 = *(const float4*)p, v1 = *(const float4*)(p + 4);
        ushort t[8] = {f2b(v0.x), f2b(v0.y), f2b(v0.z), f2b(v0.w),
                       f2b(v1.x), f2b(v1.y), f2b(v1.z), f2b(v1.w)};
        *(uint4*)&As[row][quad * 8] = *(uint4*)t;
    }
    {
        const float* p = B + (size_t)row * ldb + k0 + quad * 8;
        float4 v0 = *(const float4*)p, v1 = *(const float4*)(p + 4);
        ushort t[8] = {f2b(v0.x), f2b(v0.y), f2b(v0.z), f2b(v0.w),
                       f2b(v1.x), f2b(v1.y), f2b(v1.z), f2b(v1.w)};
        *(uint4*)&Bs[row][quad * 8] = *(uint4*)t;
    }
}

__device__ __forceinline__ void stage_b16(const ushort* __restrict__ A, const ushort* __restrict__ B,
                                          int lda, int ldb, int k0,
                                          short (*As)[LDS_LD], short (*Bs)[LDS_LD], int tid) {
    const int row = tid >> 2, quad = tid & 3;
    uint4 va = *(const uint4*)(A + (size_t)row * lda + k0 + quad * 8);
    *(uint4*)&As[row][quad * 8] = va;
    uint4 vb = *(const uint4*)(B + (size_t)row * ldb + k0 + quad * 8);
    *(uint4*)&Bs[row][quad * 8] = vb;
}

__device__ __forceinline__ void mfma_step(const short (*As)[LDS_LD], const short (*Bs)[LDS_LD],
                                          f32x4 acc[2][2], int lane, int wr, int wc) {
    const int kb = (lane >> 4) * 8;
    const int r  = lane & 15;
    bf16x8 a0 = *(const bf16x8*)&As[wr * 32 + r][kb];
    bf16x8 a1 = *(const bf16x8*)&As[wr * 32 + 16 + r][kb];
    bf16x8 b0 = *(const bf16x8*)&Bs[wc * 32 + r][kb];
    bf16x8 b1 = *(const bf16x8*)&Bs[wc * 32 + 16 + r][kb];
    acc[0][0] = __builtin_amdgcn_mfma_f32_16x16x32_bf16(a0, b0, acc[0][0], 0, 0, 0);
    acc[0][1] = __builtin_amdgcn_mfma_f32_16x16x32_bf16(a0, b1, acc[0][1], 0, 0, 0);
    acc[1][0] = __builtin_amdgcn_mfma_f32_16x16x32_bf16(a1, b0, acc[1][0], 0, 0, 0);
    acc[1][1] = __builtin_amdgcn_mfma_f32_16x16x32_bf16(a1, b1, acc[1][1], 0, 0, 0);
}

// ---------------------------------------------------------------------------
// QKV. z=0: q[t][n] = sum x[t,k] Wq[n,k];  z=1: same for k.
// z=2: vT[e][s] = sum Wv[e,k] x[s,k]   (operand swap -> transposed V free).
// Outputs bf16.
// ---------------------------------------------------------------------------
__global__ __launch_bounds__(256) void qkv_mfma(const float* __restrict__ x,
                                                const float* __restrict__ Wq,
                                                const float* __restrict__ Wk,
                                                const float* __restrict__ Wv,
                                                ushort* __restrict__ qb,
                                                ushort* __restrict__ kb,
                                                ushort* __restrict__ vT) {
    __shared__ short As[64][LDS_LD];
    __shared__ short Bs[64][LDS_LD];
    const int tid = threadIdx.x, lane = tid & 63, w = tid >> 6;
    const int wr = w >> 1, wc = w & 1;
    const int z = blockIdx.z;
    int m0, n0, ldc;
    const float *A, *B;
    ushort* C;
    if (z < 2) {
        m0 = blockIdx.x << 6;  n0 = blockIdx.y << 6;   // M=2048 (t), N=512 (n)
        A = x;  B = (z == 0) ? Wq : Wk;  C = (z == 0) ? qb : kb;  ldc = 512;
    } else {
        m0 = blockIdx.y << 6;  n0 = blockIdx.x << 6;   // M=512 (e), N=2048 (s)
        A = Wv;  B = x;  C = vT;  ldc = 2048;
    }
    f32x4 acc[2][2] = {};
    for (int k0 = 0; k0 < 512; k0 += 32) {
        stage_f32(A + (size_t)m0 * 512, B + (size_t)n0 * 512, 512, 512, k0, As, Bs, tid);
        __syncthreads();
        mfma_step(As, Bs, acc, lane, wr, wc);
        __syncthreads();
    }
    const int rb = (lane >> 4) << 2, cc = lane & 15;
#pragma unroll
    for (int fr = 0; fr < 2; ++fr)
#pragma unroll
        for (int fc = 0; fc < 2; ++fc) {
            int row = m0 + wr * 32 + fr * 16 + rb;
            int col = n0 + wc * 32 + fc * 16 + cc;
#pragma unroll
            for (int r = 0; r < 4; ++r)
                C[(size_t)(row + r) * ldc + col] = f2b(acc[fr][fc][r]);
        }
}

// ---------------------------------------------------------------------------
// Scores: S[t][s] = (q . k) * 1/sqrt(512), fp32 out.
// ---------------------------------------------------------------------------
__global__ __launch_bounds__(256) void scores_mfma(const ushort* __restrict__ qb,
                                                   const ushort* __restrict__ kb,
                                                   float* __restrict__ sb) {
    __shared__ short As[64][LDS_LD];
    __shared__ short Bs[64][LDS_LD];
    const int tid = threadIdx.x, lane = tid & 63, w = tid >> 6;
    const int wr = w >> 1, wc = w & 1;
    const int m0 = blockIdx.x << 6, n0 = blockIdx.y << 6, z = blockIdx.z;
    const ushort* A = qb + (size_t)z * 1024 * 512 + (size_t)m0 * 512;
    const ushort* B = kb + (size_t)z * 1024 * 512 + (size_t)n0 * 512;
    float* C = sb + (size_t)z * 1024 * 1024;
    f32x4 acc[2][2] = {};
    for (int k0 = 0; k0 < 512; k0 += 32) {
        stage_b16(A, B, 512, 512, k0, As, Bs, tid);
        __syncthreads();
        mfma_step(As, Bs, acc, lane, wr, wc);
        __syncthreads();
    }
    const float scale = 0.044194173824159216f;   // 1/sqrt(512)
    const int rb = (lane >> 4) << 2, cc = lane & 15;
#pragma unroll
    for (int fr = 0; fr < 2; ++fr)
#pragma unroll
        for (int fc = 0; fc < 2; ++fc) {
            int row = m0 + wr * 32 + fr * 16 + rb;
            int col = n0 + wc * 32 + fc * 16 + cc;
#pragma unroll
            for (int r = 0; r < 4; ++r)
                C[(size_t)(row + r) * 1024 + col] = acc[fr][fc][r] * scale;
        }
}

// ---------------------------------------------------------------------------
// Row softmax (1024 wide), fp32 in -> bf16 weights out.
// ---------------------------------------------------------------------------
__global__ __launch_bounds__(256) void softmax_kernel(const float* __restrict__ S,
                                                      ushort* __restrict__ W) {
    const int row = blockIdx.x, tid = threadIdx.x;
    const float* p = S + (size_t)row * 1024;
    float4 v = ((const float4*)p)[tid];
    float m = fmaxf(fmaxf(v.x, v.y), fmaxf(v.z, v.w));
#pragma unroll
    for (int off = 32; off; off >>= 1) m = fmaxf(m, __shfl_xor(m, off));
    __shared__ float sm[4];
    __shared__ float ss[4];
    const int wid = tid >> 6, lane = tid & 63;
    if (lane == 0) sm[wid] = m;
    __syncthreads();
    m = fmaxf(fmaxf(sm[0], sm[1]), fmaxf(sm[2], sm[3]));
    float e0 = expf(v.x - m), e1 = expf(v.y - m), e2 = expf(v.z - m), e3 = expf(v.w - m);
    float s = e0 + e1 + e2 + e3;
#pragma unroll
    for (int off = 32; off; off >>= 1) s += __shfl_xor(s, off);
    if (lane == 0) ss[wid] = s;
    __syncthreads();
    s = ss[0] + ss[1] + ss[2] + ss[3];
    float r = 1.0f / s;
    ushort4 o = {f2b(e0 * r), f2b(e1 * r), f2b(e2 * r), f2b(e3 * r)};
    ((ushort4*)(W + (size_t)row * 1024))[tid] = o;
}

// ---------------------------------------------------------------------------
// PV: o[t][e] = sum_s w[t,s] vT[e,s]; epilogue out = cos(o)*A[e&7]-sin(o)*B[e&7].
// ---------------------------------------------------------------------------
__global__ __launch_bounds__(256) void pv_mfma(const ushort* __restrict__ wb,
                                               const ushort* __restrict__ vT,
                                               float* __restrict__ out,
                                               const float* __restrict__ ab) {
    __shared__ short As[64][LDS_LD];
    __shared__ short Bs[64][LDS_LD];
    const int tid = threadIdx.x, lane = tid & 63, w = tid >> 6;
    const int wr = w >> 1, wc = w & 1;
    const int m0 = blockIdx.x << 6, n0 = blockIdx.y << 6, z = blockIdx.z;
    const ushort* A = wb + (size_t)z * 1024 * 1024 + (size_t)m0 * 1024;   // [t][s]
    const ushort* B = vT + (size_t)n0 * 2048 + z * 1024;                  // [e][s]
    float* C = out + (size_t)z * 1024 * 512;
    f32x4 acc[2][2] = {};
    for (int k0 = 0; k0 < 1024; k0 += 32) {
        stage_b16(A, B, 1024, 2048, k0, As, Bs, tid);
        __syncthreads();
        mfma_step(As, Bs, acc, lane, wr, wc);
        __syncthreads();
    }
    const float Aq = ab[lane & 7], Bq = ab[8 + (lane & 7)];
    const int rb = (lane >> 4) << 2, cc = lane & 15;
#pragma unroll
    for (int fr = 0; fr < 2; ++fr)
#pragma unroll
        for (int fc = 0; fc < 2; ++fc) {
            int row = m0 + wr * 32 + fr * 16 + rb;
            int col = n0 + wc * 32 + fc * 16 + cc;
#pragma unroll
            for (int r = 0; r < 4; ++r) {
                float sn, cs;
                sincosf(acc[fr][fc][r], &sn, &cs);
                C[(size_t)(row + r) * 512 + col] = cs * Aq - sn * Bq;
            }
        }
}

// ---------------------------------------------------------------------------
extern "C" void kernel_launch(void* const* d_in, const int* in_sizes, int n_in,
                              void* d_out, int out_size, void* d_ws, size_t ws_size,
                              hipStream_t stream) {
    const float* x      = (const float*)d_in[0];
    const float* Wq     = (const float*)d_in[1];
    const float* Wk     = (const float*)d_in[2];
    const float* Wv     = (const float*)d_in[3];
    const float* params = (const float*)d_in[4];
    float* out = (float*)d_out;

    char* base = (char*)d_ws;
    float*  ab = (float*)base;                                   // 64 B (pad to 256)
    ushort* qb = (ushort*)(base + 256);                          // 2048x512 bf16
    ushort* kb = qb + 2048 * 512;                                // 2048x512 bf16
    ushort* vT = kb + 2048 * 512;                                // 512x2048 bf16
    float*  sb = (float*)(base + 256 + (size_t)3 * 2048 * 512 * 2);  // 2x1024x1024 f32
    ushort* wb = (ushort*)((char*)sb + (size_t)2 * 1024 * 1024 * 4); // 2x1024x1024 bf16

    hipLaunchKernelGGL(qconsts_kernel, dim3(1), dim3(256), 0, stream, params, ab);
    hipLaunchKernelGGL(qkv_mfma, dim3(32, 8, 3), dim3(256), 0, stream,
                       x, Wq, Wk, Wv, qb, kb, vT);
    hipLaunchKernelGGL(scores_mfma, dim3(16, 16, 2), dim3(256), 0, stream, qb, kb, sb);
    hipLaunchKernelGGL(softmax_kernel, dim3(2048), dim3(256), 0, stream, sb, wb);
    hipLaunchKernelGGL(pv_mfma, dim3(16, 8, 2), dim3(256), 0, stream, wb, vT, out, ab);
}

// Round 4
// 106.200 us; speedup vs baseline: 1.9704x; 1.1890x over previous
//
#include <hip/hip_runtime.h>
#include <math.h>

typedef __attribute__((ext_vector_type(8))) short bf16x8;
typedef __attribute__((ext_vector_type(4))) float f32x4;

#define LD 72   // shorts per LDS row: 64 bf16 + 8 pad -> ds_read_b128 2-way only

__device__ __forceinline__ ushort f2b(float f) {   // fp32 -> bf16 RNE
    unsigned u = __float_as_uint(f);
    return (ushort)((u + 0x7FFFu + ((u >> 16) & 1u)) >> 16);
}

// ---------------------------------------------------------------------------
// Pre-convert fp32 inputs to bf16. z=0: x (2048x512), z=1..3: Wq/Wk/Wv (512x512)
// ---------------------------------------------------------------------------
__global__ __launch_bounds__(256) void cvt_kernel(const float* __restrict__ x,
                                                  const float* __restrict__ wq,
                                                  const float* __restrict__ wk,
                                                  const float* __restrict__ wv,
                                                  ushort* __restrict__ xb,
                                                  ushort* __restrict__ wqb,
                                                  ushort* __restrict__ wkb,
                                                  ushort* __restrict__ wvb) {
    const int z = blockIdx.y;
    const float* src = (z == 0) ? x : (z == 1) ? wq : (z == 2) ? wk : wv;
    ushort* dst = (z == 0) ? xb : (z == 1) ? wqb : (z == 2) ? wkb : wvb;
    const int n = (z == 0) ? (2048 * 512) : (512 * 512);
    const int i = (blockIdx.x * 256 + threadIdx.x) * 8;
    if (i >= n) return;
    float4 v0 = *(const float4*)(src + i);
    float4 v1 = *(const float4*)(src + i + 4);
    ushort t[8] = {f2b(v0.x), f2b(v0.y), f2b(v0.z), f2b(v0.w),
                   f2b(v1.x), f2b(v1.y), f2b(v1.z), f2b(v1.w)};
    *(uint4*)(dst + i) = *(uint4*)t;
}

// ---------------------------------------------------------------------------
// Quantum constants: A_q=<Z_q>, B_q=<X_q> of psi0; circuit collapses to
// z_q(theta)=cos(theta)A_q - sin(theta)B_q. Wave-level reductions (no barrier).
// ---------------------------------------------------------------------------
__global__ __launch_bounds__(256) void qconsts_kernel(const float* __restrict__ params,
                                                      float* __restrict__ ab) {
    __shared__ float st[256];
    __shared__ float red[64];
    const int tid = threadIdx.x;
    st[tid] = (tid == 0) ? 1.0f : 0.0f;
    __syncthreads();
    for (int l = 0; l < 2; ++l) {
        for (int q = 0; q < 8; ++q) {
            float h = 0.5f * params[l * 8 + q];
            float c = cosf(h), s = sinf(h);
            int str = 1 << (7 - q);
            if ((tid & str) == 0) {
                float s0 = st[tid], s1 = st[tid + str];
                st[tid]       = c * s0 - s * s1;
                st[tid + str] = s * s0 + c * s1;
            }
            __syncthreads();
        }
        for (int q = 0; q < 8; ++q) {
            int cw = q, tw = (q + 1) & 7;
            int cs = 1 << (7 - cw), ts = 1 << (7 - tw);
            if ((tid & cs) && !(tid & ts)) {
                float a = st[tid], b = st[tid ^ ts];
                st[tid] = b;
                st[tid ^ ts] = a;
            }
            __syncthreads();
        }
    }
    const float amp = st[tid];
    float v[16];
#pragma unroll
    for (int q = 0; q < 8; ++q) {
        int str = 1 << (7 - q);
        v[q]     = amp * amp * ((tid & str) ? -1.0f : 1.0f);
        v[8 + q] = ((tid & str) == 0) ? 2.0f * amp * st[tid ^ str] : 0.0f;
    }
#pragma unroll
    for (int off = 32; off; off >>= 1)
#pragma unroll
        for (int q = 0; q < 16; ++q) v[q] += __shfl_xor(v[q], off);
    const int lane = tid & 63, wid = tid >> 6;
    if (lane == 0)
#pragma unroll
        for (int q = 0; q < 16; ++q) red[wid * 16 + q] = v[q];
    __syncthreads();
    if (tid < 16) ab[tid] = red[tid] + red[16 + tid] + red[32 + tid] + red[48 + tid];
}

// ---------------------------------------------------------------------------
// Tile staging helpers (bf16, K-contiguous rows)
// ---------------------------------------------------------------------------
__device__ __forceinline__ void load64(const ushort* __restrict__ p, int ld, int k0,
                                       int tid, uint4 r[2]) {
#pragma unroll
    for (int c = 0; c < 2; ++c) {
        int idx = tid + 256 * c;
        int row = idx >> 3, col = (idx & 7) * 8;
        r[c] = *(const uint4*)(p + (size_t)row * ld + k0 + col);
    }
}
__device__ __forceinline__ void store64(short (*S)[LD], int tid, const uint4 r[2]) {
#pragma unroll
    for (int c = 0; c < 2; ++c) {
        int idx = tid + 256 * c;
        int row = idx >> 3, col = (idx & 7) * 8;
        *(uint4*)&S[row][col] = r[c];
    }
}

// 64x64 tile MFMA step over BK=64 (4 waves, each 32x32 = 2x2 frags)
__device__ __forceinline__ void mfma64(const short (*As)[LD], const short (*Bs)[LD],
                                       f32x4 acc[2][2], int lane, int wr, int wc) {
    const int r = lane & 15, kb = (lane >> 4) * 8;
#pragma unroll
    for (int c = 0; c < 2; ++c) {
        const int k = c * 32 + kb;
        bf16x8 a0 = *(const bf16x8*)&As[wr * 32 + r][k];
        bf16x8 a1 = *(const bf16x8*)&As[wr * 32 + 16 + r][k];
        bf16x8 b0 = *(const bf16x8*)&Bs[wc * 32 + r][k];
        bf16x8 b1 = *(const bf16x8*)&Bs[wc * 32 + 16 + r][k];
        acc[0][0] = __builtin_amdgcn_mfma_f32_16x16x32_bf16(a0, b0, acc[0][0], 0, 0, 0);
        acc[0][1] = __builtin_amdgcn_mfma_f32_16x16x32_bf16(a0, b1, acc[0][1], 0, 0, 0);
        acc[1][0] = __builtin_amdgcn_mfma_f32_16x16x32_bf16(a1, b0, acc[1][0], 0, 0, 0);
        acc[1][1] = __builtin_amdgcn_mfma_f32_16x16x32_bf16(a1, b1, acc[1][1], 0, 0, 0);
    }
}

// ---------------------------------------------------------------------------
// QKV (bf16 in/out). z=0/1: q,k [t][n] = x . W^T.  z=2: vT[e][s] = Wv . x^T.
// Double-buffered LDS, 1 barrier per K-step.
// ---------------------------------------------------------------------------
__global__ __launch_bounds__(256) void qkv_mfma(const ushort* __restrict__ xb,
                                                const ushort* __restrict__ wqb,
                                                const ushort* __restrict__ wkb,
                                                const ushort* __restrict__ wvb,
                                                ushort* __restrict__ qb,
                                                ushort* __restrict__ kb,
                                                ushort* __restrict__ vT) {
    __shared__ short As[2][64][LD];
    __shared__ short Bs[2][64][LD];
    const int tid = threadIdx.x, lane = tid & 63, w = tid >> 6;
    const int wr = w >> 1, wc = w & 1;
    const int z = blockIdx.z;
    int m0, n0, ldc;
    const ushort *A, *B;
    ushort* C;
    if (z < 2) {
        m0 = blockIdx.x << 6;  n0 = blockIdx.y << 6;
        A = xb;  B = (z == 0) ? wqb : wkb;  C = (z == 0) ? qb : kb;  ldc = 512;
    } else {
        m0 = blockIdx.y << 6;  n0 = blockIdx.x << 6;
        A = wvb;  B = xb;  C = vT;  ldc = 2048;
    }
    const ushort* Ap = A + (size_t)m0 * 512;
    const ushort* Bp = B + (size_t)n0 * 512;
    uint4 ra[2], rb[2];
    load64(Ap, 512, 0, tid, ra);
    load64(Bp, 512, 0, tid, rb);
    store64(As[0], tid, ra);
    store64(Bs[0], tid, rb);
    __syncthreads();
    f32x4 acc[2][2] = {};
    for (int t = 0; t < 8; ++t) {
        if (t < 7) {
            load64(Ap, 512, (t + 1) * 64, tid, ra);
            load64(Bp, 512, (t + 1) * 64, tid, rb);
        }
        mfma64(As[t & 1], Bs[t & 1], acc, lane, wr, wc);
        if (t < 7) {
            store64(As[(t & 1) ^ 1], tid, ra);
            store64(Bs[(t & 1) ^ 1], tid, rb);
        }
        __syncthreads();
    }
    const int rb2 = (lane >> 4) << 2, cc = lane & 15;
#pragma unroll
    for (int fr = 0; fr < 2; ++fr)
#pragma unroll
        for (int fc = 0; fc < 2; ++fc) {
            int row = m0 + wr * 32 + fr * 16 + rb2;
            int col = n0 + wc * 32 + fc * 16 + cc;
#pragma unroll
            for (int r = 0; r < 4; ++r)
                C[(size_t)(row + r) * ldc + col] = f2b(acc[fr][fc][r]);
        }
}

// ---------------------------------------------------------------------------
// Scores: S = (q.k^T)/sqrt(512), fp32 out.
// ---------------------------------------------------------------------------
__global__ __launch_bounds__(256) void scores_mfma(const ushort* __restrict__ qb,
                                                   const ushort* __restrict__ kb,
                                                   float* __restrict__ sb) {
    __shared__ short As[2][64][LD];
    __shared__ short Bs[2][64][LD];
    const int tid = threadIdx.x, lane = tid & 63, w = tid >> 6;
    const int wr = w >> 1, wc = w & 1;
    const int m0 = blockIdx.x << 6, n0 = blockIdx.y << 6, z = blockIdx.z;
    const ushort* Ap = qb + (size_t)z * 1024 * 512 + (size_t)m0 * 512;
    const ushort* Bp = kb + (size_t)z * 1024 * 512 + (size_t)n0 * 512;
    float* C = sb + (size_t)z * 1024 * 1024;
    uint4 ra[2], rb[2];
    load64(Ap, 512, 0, tid, ra);
    load64(Bp, 512, 0, tid, rb);
    store64(As[0], tid, ra);
    store64(Bs[0], tid, rb);
    __syncthreads();
    f32x4 acc[2][2] = {};
    for (int t = 0; t < 8; ++t) {
        if (t < 7) {
            load64(Ap, 512, (t + 1) * 64, tid, ra);
            load64(Bp, 512, (t + 1) * 64, tid, rb);
        }
        mfma64(As[t & 1], Bs[t & 1], acc, lane, wr, wc);
        if (t < 7) {
            store64(As[(t & 1) ^ 1], tid, ra);
            store64(Bs[(t & 1) ^ 1], tid, rb);
        }
        __syncthreads();
    }
    const float scale = 0.044194173824159216f;   // 1/sqrt(512)
    const int rb2 = (lane >> 4) << 2, cc = lane & 15;
#pragma unroll
    for (int fr = 0; fr < 2; ++fr)
#pragma unroll
        for (int fc = 0; fc < 2; ++fc) {
            int row = m0 + wr * 32 + fr * 16 + rb2;
            int col = n0 + wc * 32 + fc * 16 + cc;
#pragma unroll
            for (int r = 0; r < 4; ++r)
                C[(size_t)(row + r) * 1024 + col] = acc[fr][fc][r] * scale;
        }
}

// ---------------------------------------------------------------------------
// Row softmax (1024 wide), fp32 in -> bf16 out.
// ---------------------------------------------------------------------------
__global__ __launch_bounds__(256) void softmax_kernel(const float* __restrict__ S,
                                                      ushort* __restrict__ W) {
    const int row = blockIdx.x, tid = threadIdx.x;
    const float* p = S + (size_t)row * 1024;
    float4 v = ((const float4*)p)[tid];
    float m = fmaxf(fmaxf(v.x, v.y), fmaxf(v.z, v.w));
#pragma unroll
    for (int off = 32; off; off >>= 1) m = fmaxf(m, __shfl_xor(m, off));
    __shared__ float sm[4];
    __shared__ float ss[4];
    const int wid = tid >> 6, lane = tid & 63;
    if (lane == 0) sm[wid] = m;
    __syncthreads();
    m = fmaxf(fmaxf(sm[0], sm[1]), fmaxf(sm[2], sm[3]));
    float e0 = expf(v.x - m), e1 = expf(v.y - m), e2 = expf(v.z - m), e3 = expf(v.w - m);
    float s = e0 + e1 + e2 + e3;
#pragma unroll
    for (int off = 32; off; off >>= 1) s += __shfl_xor(s, off);
    if (lane == 0) ss[wid] = s;
    __syncthreads();
    s = ss[0] + ss[1] + ss[2] + ss[3];
    float r = 1.0f / s;
    ushort4 o = {f2b(e0 * r), f2b(e1 * r), f2b(e2 * r), f2b(e3 * r)};
    ((ushort4*)(W + (size_t)row * 1024))[tid] = o;
}

// ---------------------------------------------------------------------------
// PV: o[t][e] = sum_s w[t,s] vT[e,s]; epilogue cos(o)A[e&7]-sin(o)B[e&7].
// 32x64 tile (grid 512 -> 2 blocks/CU), K=1024.
// ---------------------------------------------------------------------------
__global__ __launch_bounds__(256) void pv_mfma(const ushort* __restrict__ wb,
                                               const ushort* __restrict__ vT,
                                               float* __restrict__ out,
                                               const float* __restrict__ ab) {
    __shared__ short As[2][32][LD];
    __shared__ short Bs[2][64][LD];
    const int tid = threadIdx.x, lane = tid & 63, w = tid >> 6;
    const int wr = w >> 1, wc = w & 1;           // wr: 16-row half, wc: 32-col half
    const int m0 = blockIdx.x << 5, n0 = blockIdx.y << 6, z = blockIdx.z;
    const ushort* Ap = wb + (size_t)z * 1024 * 1024 + (size_t)m0 * 1024;  // [t][s]
    const ushort* Bp = vT + (size_t)n0 * 2048 + z * 1024;                 // [e][s]
    float* C = out + (size_t)z * 1024 * 512;

    uint4 ra, rbv[2];
    const int arow = tid >> 3, acol = (tid & 7) * 8;   // 32x8 uint4 = 256
    ra = *(const uint4*)(Ap + (size_t)arow * 1024 + acol);
    load64(Bp, 2048, 0, tid, rbv);
    *(uint4*)&As[0][arow][acol] = ra;
    store64(Bs[0], tid, rbv);
    __syncthreads();
    f32x4 acc[2] = {};
    for (int t = 0; t < 16; ++t) {
        if (t < 15) {
            ra = *(const uint4*)(Ap + (size_t)arow * 1024 + (t + 1) * 64 + acol);
            load64(Bp, 2048, (t + 1) * 64, tid, rbv);
        }
        {
            const short (*Asb)[LD] = As[t & 1];
            const short (*Bsb)[LD] = Bs[t & 1];
            const int r = lane & 15, kb = (lane >> 4) * 8;
#pragma unroll
            for (int c = 0; c < 2; ++c) {
                const int k = c * 32 + kb;
                bf16x8 a0 = *(const bf16x8*)&Asb[wr * 16 + r][k];
                bf16x8 b0 = *(const bf16x8*)&Bsb[wc * 32 + r][k];
                bf16x8 b1 = *(const bf16x8*)&Bsb[wc * 32 + 16 + r][k];
                acc[0] = __builtin_amdgcn_mfma_f32_16x16x32_bf16(a0, b0, acc[0], 0, 0, 0);
                acc[1] = __builtin_amdgcn_mfma_f32_16x16x32_bf16(a0, b1, acc[1], 0, 0, 0);
            }
        }
        if (t < 15) {
            *(uint4*)&As[(t & 1) ^ 1][arow][acol] = ra;
            store64(Bs[(t & 1) ^ 1], tid, rbv);
        }
        __syncthreads();
    }
    const float Aq = ab[lane & 7], Bq = ab[8 + (lane & 7)];
    const int rb2 = (lane >> 4) << 2, cc = lane & 15;
#pragma unroll
    for (int fc = 0; fc < 2; ++fc) {
        int row = m0 + wr * 16 + rb2;
        int col = n0 + wc * 32 + fc * 16 + cc;
#pragma unroll
        for (int r = 0; r < 4; ++r) {
            float sn, cs;
            sincosf(acc[fc][r], &sn, &cs);
            C[(size_t)(row + r) * 512 + col] = cs * Aq - sn * Bq;
        }
    }
}

// ---------------------------------------------------------------------------
extern "C" void kernel_launch(void* const* d_in, const int* in_sizes, int n_in,
                              void* d_out, int out_size, void* d_ws, size_t ws_size,
                              hipStream_t stream) {
    const float* x      = (const float*)d_in[0];
    const float* Wq     = (const float*)d_in[1];
    const float* Wk     = (const float*)d_in[2];
    const float* Wv     = (const float*)d_in[3];
    const float* params = (const float*)d_in[4];
    float* out = (float*)d_out;

    char* base = (char*)d_ws;
    float*  ab  = (float*)base;                         // 64 B (pad to 256)
    ushort* xb  = (ushort*)(base + 256);                // 2048x512
    ushort* wqb = xb + 2048 * 512;                      // 512x512
    ushort* wkb = wqb + 512 * 512;
    ushort* wvb = wkb + 512 * 512;
    ushort* qb  = wvb + 512 * 512;                      // 2048x512
    ushort* kb  = qb + 2048 * 512;                      // 2048x512
    ushort* vT  = kb + 2048 * 512;                      // 512x2048
    float*  sb  = (float*)(vT + 2048 * 512);            // 2x1024x1024 f32
    ushort* wb  = (ushort*)(sb + 2 * 1024 * 1024);      // 2x1024x1024 bf16

    hipLaunchKernelGGL(cvt_kernel, dim3(512, 4), dim3(256), 0, stream,
                       x, Wq, Wk, Wv, xb, wqb, wkb, wvb);
    hipLaunchKernelGGL(qconsts_kernel, dim3(1), dim3(256), 0, stream, params, ab);
    hipLaunchKernelGGL(qkv_mfma, dim3(32, 8, 3), dim3(256), 0, stream,
                       xb, wqb, wkb, wvb, qb, kb, vT);
    hipLaunchKernelGGL(scores_mfma, dim3(16, 16, 2), dim3(256), 0, stream, qb, kb, sb);
    hipLaunchKernelGGL(softmax_kernel, dim3(2048), dim3(256), 0, stream, sb, wb);
    hipLaunchKernelGGL(pv_mfma, dim3(32, 8, 2), dim3(256), 0, stream, wb, vT, out, ab);
}